// Round 6
// baseline (3852.126 us; speedup 1.0000x reference)
//
#include <hip/hip_runtime.h>
#include <math.h>

#define NN 4000
#define KC 384   // OpenBLAS SGEMM_DEFAULT_Q (Haswell/Zen): k-blocking granularity

// ===========================================================================
// np-f32 mirror pipeline, v2: adds OpenBLAS KC=384 k-blocking.
// Each output dot = fold over k-blocks: blk = fma-chain over 384 k's (from 0),
// acc = fadd_rn(acc, blk) at each block boundary — matching OpenBLAS sgemm's
// store-then-add panel accumulation. All else identical to round-5 mirror:
//  - numpy pairwise_sum (blocksize 128, 8-acc base) for norms / L1 rowsums
//  - correctly-rounded f32 elementwise ops
//  - exact 32-bit radix rank-select for param
// ===========================================================================

template<int EPI, bool TRANSB>
__global__ __launch_bounds__(256)
void gemm_k(const float* __restrict__ A, const float* __restrict__ B,
            float* __restrict__ C, int M, int N, int K,
            const float* __restrict__ bias, const float* __restrict__ wn)
{
    __shared__ float As[16][68];
    __shared__ float Bs[16][68];
    const int tid = threadIdx.x;
    const int tx = tid & 15, ty = tid >> 4;
    const int bm = blockIdx.y * 64, bn = blockIdx.x * 64;

    float acc[4][4] = {};
    float blk[4][4] = {};

    for (int kb = 0; kb < K; kb += KC) {
        const int kend = (kb + KC < K) ? (kb + KC) : K;
        for (int k0 = kb; k0 < kend; k0 += 16) {
            {
                const int kk = tid & 15, r0 = tid >> 4;
#pragma unroll
                for (int it = 0; it < 4; ++it) {
                    int r = r0 + it * 16;
                    int gr = bm + r, gk = k0 + kk;
                    float v = 0.f;
                    if (gr < M && gk < K && gk < kend) v = A[(size_t)gr * K + gk];
                    As[kk][r] = v;
                }
            }
            if (!TRANSB) {
                const int c = tid & 63, k0t = tid >> 6;
#pragma unroll
                for (int it = 0; it < 4; ++it) {
                    int kk = k0t + it * 4;
                    int gk = k0 + kk, gc = bn + c;
                    float v = 0.f;
                    if (gk < K && gk < kend && gc < N) v = B[(size_t)gk * N + gc];
                    Bs[kk][c] = v;
                }
            } else {
                const int kk = tid & 15, c0 = tid >> 4;
#pragma unroll
                for (int it = 0; it < 4; ++it) {
                    int c = c0 + it * 16;
                    int gc = bn + c, gk = k0 + kk;
                    float v = 0.f;
                    if (gc < N && gk < K && gk < kend) v = B[(size_t)gc * K + gk];
                    Bs[kk][c] = v;
                }
            }
            __syncthreads();
#pragma unroll
            for (int kk = 0; kk < 16; ++kk) {
                float a[4], b[4];
#pragma unroll
                for (int i = 0; i < 4; ++i) a[i] = As[kk][ty + i * 16];
#pragma unroll
                for (int j = 0; j < 4; ++j) b[j] = Bs[kk][tx + j * 16];
#pragma unroll
                for (int i = 0; i < 4; ++i)
#pragma unroll
                    for (int j = 0; j < 4; ++j)
                        blk[i][j] = fmaf(a[i], b[j], blk[i][j]);  // strict asc. k
            }
            __syncthreads();
        }
        // fold k-block into running total (OpenBLAS store-then-add semantics)
#pragma unroll
        for (int i = 0; i < 4; ++i)
#pragma unroll
            for (int j = 0; j < 4; ++j) {
                acc[i][j] = __fadd_rn(acc[i][j], blk[i][j]);
                blk[i][j] = 0.f;
            }
    }

#pragma unroll
    for (int i = 0; i < 4; ++i) {
        int r = bm + ty + i * 16;
        if (r >= M) continue;
#pragma unroll
        for (int j = 0; j < 4; ++j) {
            int c = bn + tx + j * 16;
            if (c >= N) continue;
            float v = acc[i][j];
            if (EPI == 0) {
                C[(size_t)r * N + c] = v;
            } else if (EPI == 1) {
                float s = __fadd_rn(v, bias[c]);
                C[(size_t)r * N + c] = (s >= 0.f) ? s : __fmul_rn(0.25f, s);
            } else {
                float den = fmaxf(__fmul_rn(wn[r], wn[c]), 1e-8f);
                C[(size_t)r * N + c] = __fsub_rn(1.0f, __fdiv_rn(v, den));
            }
        }
    }
}

// ---------------------------------------------------------------------------
// numpy pairwise_sum exact replica. XF=0: fl(v*v); XF=1: |v|.
// ---------------------------------------------------------------------------
template<int XF>
__device__ float xf(float v)
{
    if (XF == 0) return __fmul_rn(v, v);
    return fabsf(v);
}

template<int XF>
__device__ float np_pairwise(const float* a, int n)
{
    if (n < 8) {
        float r = 0.f;
        for (int i = 0; i < n; ++i) r = __fadd_rn(r, xf<XF>(a[i]));
        return r;
    }
    if (n <= 128) {
        float r[8];
#pragma unroll
        for (int j = 0; j < 8; ++j) r[j] = xf<XF>(a[j]);
        int i = 8;
        const int lim = n - (n & 7);
        for (; i < lim; i += 8)
#pragma unroll
            for (int j = 0; j < 8; ++j) r[j] = __fadd_rn(r[j], xf<XF>(a[i + j]));
        float res = __fadd_rn(__fadd_rn(__fadd_rn(r[0], r[1]), __fadd_rn(r[2], r[3])),
                              __fadd_rn(__fadd_rn(r[4], r[5]), __fadd_rn(r[6], r[7])));
        for (; i < n; ++i) res = __fadd_rn(res, xf<XF>(a[i]));
        return res;
    }
    int n2 = (n / 2) & ~7;
    return __fadd_rn(np_pairwise<XF>(a, n2), np_pairwise<XF>(a + n2, n - n2));
}

__global__ __launch_bounds__(64)
void rownorm_np_k(const float* __restrict__ X, float* __restrict__ wn, int D)
{
    int row = blockIdx.x * 64 + threadIdx.x;
    if (row >= NN) return;
    wn[row] = __fsqrt_rn(np_pairwise<0>(X + (size_t)row * D, D));
}

__global__ __launch_bounds__(64)
void rowabs_np_k(const float* __restrict__ A, float* __restrict__ rs, int n)
{
    int row = blockIdx.x * 64 + threadIdx.x;
    if (row >= NN) return;
    rs[row] = fmaxf(np_pairwise<1>(A + (size_t)row * n, n), 1e-12f);
}

// ---------------------------------------------------------------------------
// exact rank select (radix, 32-bit monotone keys): value at sorted index k*NN
// ---------------------------------------------------------------------------
__global__ void init_k(unsigned* __restrict__ hist, unsigned* __restrict__ state,
                       const void* __restrict__ epn)
{
    hist[threadIdx.x] = 0;
    if (threadIdx.x == 0) {
        int k = ((const int*)epn)[0];
        if (k <= 0 || k > 4000) {
            float f = ((const float*)epn)[0];
            if (f > 0.f && f <= 4000.f) k = (int)f;
            else {
                long long ll = ((const long long*)epn)[0];
                if (ll > 0 && ll <= 4000) k = (int)ll;
                else {
                    double dd = ((const double*)epn)[0];
                    k = (dd > 0.0 && dd <= 4000.0) ? (int)dd : 10;
                }
            }
        }
        state[0] = 0u;
        state[1] = (unsigned)(k * NN);
    }
}

__global__ __launch_bounds__(256)
void hist_k(const float* __restrict__ dist, unsigned* __restrict__ hist,
            const unsigned* __restrict__ state, int shift, size_t n)
{
    __shared__ unsigned lh[256];
    lh[threadIdx.x] = 0;
    __syncthreads();
    const unsigned prefix = state[0];
    const size_t stride = (size_t)gridDim.x * 256;
    for (size_t idx = (size_t)blockIdx.x * 256 + threadIdx.x; idx < n; idx += stride) {
        unsigned u = __float_as_uint(dist[idx]);
        unsigned key = (u & 0x80000000u) ? ~u : (u | 0x80000000u);
        bool ok = (shift == 24) || ((key >> (shift + 8)) == prefix);
        if (ok) atomicAdd(&lh[(key >> shift) & 0xFFu], 1u);
    }
    __syncthreads();
    if (lh[threadIdx.x]) atomicAdd(&hist[threadIdx.x], lh[threadIdx.x]);
}

__global__ __launch_bounds__(256)
void scan_k(unsigned* __restrict__ hist, unsigned* __restrict__ state,
            int shift, float* __restrict__ param)
{
    const int tid = threadIdx.x;
    unsigned h = hist[tid];
    hist[tid] = 0;
    __shared__ unsigned sh[256];
    sh[tid] = h;
    __syncthreads();
    for (int off = 1; off < 256; off <<= 1) {
        unsigned v = (tid >= off) ? sh[tid - off] : 0;
        __syncthreads();
        sh[tid] += v;
        __syncthreads();
    }
    const unsigned incl = sh[tid], excl = incl - h;
    const unsigned krem = state[1];
    if (krem >= excl && krem < incl) {
        unsigned np = (state[0] << 8) | (unsigned)tid;
        state[0] = np;
        state[1] = krem - excl;
        if (shift == 0) {
            unsigned u = (np & 0x80000000u) ? (np ^ 0x80000000u) : ~np;
            *param = __uint_as_float(u);
        }
    }
}

__global__ __launch_bounds__(256)
void thresh_k(float* __restrict__ adj, const float* __restrict__ param, int n)
{
    const int i = blockIdx.y;
    const int j = blockIdx.x * 256 + threadIdx.x;
    if (j >= n) return;
    const float p = *param;
    const size_t idx = (size_t)i * n + j;
    float d = adj[idx];
    float a = (d <= p && i != j) ? __fsub_rn(1.0f, d) : 0.0f;
    if (i == j) a = 1.0f;
    adj[idx] = a;
}

// max-symmetrize (dist bitwise symmetric -> equals numpy's (a+b·t)-a·t exactly)
__global__ __launch_bounds__(256)
void sym_k(float* __restrict__ adj, int n)
{
    const int i = blockIdx.y;
    const int j = blockIdx.x * 256 + threadIdx.x;
    if (j >= n || j <= i) return;
    const size_t ij = (size_t)i * n + j;
    const size_t ji = (size_t)j * n + i;
    float a = adj[ij], b = adj[ji];
    float m = fmaxf(a, b);
    adj[ij] = m;
    adj[ji] = m;
}

__global__ __launch_bounds__(256)
void norm_k(float* __restrict__ adj, const float* __restrict__ rs, int n)
{
    const int i = blockIdx.y;
    const int j = blockIdx.x * 256 + threadIdx.x;
    if (j >= n) return;
    const size_t idx = (size_t)i * n + j;
    adj[idx] = __fdiv_rn(adj[idx], rs[i]);
}

// ---------------------------------------------------------------------------

static inline dim3 gemm_grid(int M, int N)
{
    return dim3((N + 63) / 64, (M + 63) / 64);
}

extern "C" void kernel_launch(void* const* d_in, const int* in_sizes, int n_in,
                              void* d_out, int out_size, void* d_ws, size_t ws_size,
                              hipStream_t stream)
{
    const void*  epn  = d_in[0];
    const float* x    = (const float*)d_in[1];
    const float* adj0 = (const float*)d_in[2];
    const float* w1   = (const float*)d_in[3];
    const float* b1   = (const float*)d_in[4];
    const float* w2   = (const float*)d_in[5];
    const float* b2   = (const float*)d_in[6];
    const float* w3   = (const float*)d_in[7];
    const float* b3   = (const float*)d_in[8];
    float* out = (float*)d_out;

    char* ws = (char*)d_ws;
    float*    dist  = (float*)   ws;                       // 64,000,000 B
    float*    Tbuf  = (float*)  (ws + 64000000);           //  6,400,000
    float*    H1    = (float*)  (ws + 70400000);           //  6,400,000
    float*    H2    = (float*)  (ws + 76800000);           //  6,400,000
    float*    wn    = (float*)  (ws + 83200000);           //     16,000
    float*    rs    = (float*)  (ws + 83216000);           //     16,000
    unsigned* hist  = (unsigned*)(ws + 83232000);          //      1,024
    unsigned* state = (unsigned*)(ws + 83233024);          //          8
    float*    param = (float*)  (ws + 83233032);           //          4

    const size_t n2 = (size_t)NN * NN;
    const int shifts[4] = {24, 16, 8, 0};
    const dim3 rowgrid((NN + 255) / 256, NN);

    // ---- Layer 1: H1 = leaky(adj0 @ (x @ w1) + b1)
    gemm_k<0, false><<<gemm_grid(NN, 400), 256, 0, stream>>>(
        x, w1, Tbuf, NN, 400, 1000, nullptr, nullptr);
    gemm_k<1, false><<<gemm_grid(NN, 400), 256, 0, stream>>>(
        adj0, Tbuf, H1, NN, 400, NN, b1, nullptr);

    for (int layer = 0; layer < 2; ++layer) {
        const float* H = (layer == 0) ? H1 : H2;
        // ---- gen_adj(H)
        rownorm_np_k<<<(NN + 63) / 64, 64, 0, stream>>>(H, wn, 400);
        gemm_k<2, true><<<gemm_grid(NN, NN), 256, 0, stream>>>(
            H, H, dist, NN, NN, 400, nullptr, wn);
        init_k<<<1, 256, 0, stream>>>(hist, state, epn);
        for (int p = 0; p < 4; ++p) {
            hist_k<<<2048, 256, 0, stream>>>(dist, hist, state, shifts[p], n2);
            scan_k<<<1, 256, 0, stream>>>(hist, state, shifts[p], param);
        }
        thresh_k<<<rowgrid, 256, 0, stream>>>(dist, param, NN);
        sym_k<<<rowgrid, 256, 0, stream>>>(dist, NN);
        rowabs_np_k<<<(NN + 63) / 64, 64, 0, stream>>>(dist, rs, NN);
        norm_k<<<rowgrid, 256, 0, stream>>>(dist, rs, NN);

        if (layer == 0) {
            gemm_k<0, false><<<gemm_grid(NN, 400), 256, 0, stream>>>(
                H1, w2, Tbuf, NN, 400, 400, nullptr, nullptr);
            gemm_k<1, false><<<gemm_grid(NN, 400), 256, 0, stream>>>(
                dist, Tbuf, H2, NN, 400, NN, b2, nullptr);
        } else {
            gemm_k<0, false><<<gemm_grid(NN, 200), 256, 0, stream>>>(
                H2, w3, Tbuf, NN, 200, 400, nullptr, nullptr);
            gemm_k<1, false><<<gemm_grid(NN, 200), 256, 0, stream>>>(
                dist, Tbuf, out, NN, 200, NN, b3, nullptr);
        }
    }
}

// Round 7
// 1966.046 us; speedup vs baseline: 1.9593x; 1.9593x over previous
//
#include <hip/hip_runtime.h>
#include <math.h>

#define NN 4000
#define KC 384      // OpenBLAS SGEMM_DEFAULT_Q — fold granularity (bit-frozen)
#define LEAKY 0.25f

// ===========================================================================
// Bit-frozen arithmetic (matches np/OpenBLAS f32 reference, verified R6):
//   - per-output: blk = fmaf(a_k, b_k, blk) strict ascending k; at each
//     original-k multiple of 384: acc = __fadd_rn(acc, blk), blk = 0.
//   - reductions: numpy pairwise_sum replica; elementwise: *_rn intrinsics.
// This round only reshuffles implementation (tiling, sparsity, transpose
// staging) in ways that keep every output's operation sequence identical.
// ===========================================================================

// ---------------------------------------------------------------------------
// 128x128-tile GEMM, 256 threads, 8x8 per thread (rows/cols split +-64).
// EPI: 0 plain | 1 leaky(acc+bias[c]) | 2 1-acc/max(wn_r*wn_c,1e-8)
// ---------------------------------------------------------------------------
template<int EPI, bool TRANSB>
__global__ __launch_bounds__(256)
void gemm128_k(const float* __restrict__ A, const float* __restrict__ B,
               float* __restrict__ C, int M, int N, int K,
               const float* __restrict__ bias, const float* __restrict__ wn)
{
    __shared__ float As[16][132];
    __shared__ float Bs[16][132];
    const int tid = threadIdx.x;
    const int tx = tid & 15, ty = tid >> 4;
    const int bm = blockIdx.y * 128, bn = blockIdx.x * 128;

    float acc[8][8] = {};
    float blk[8][8] = {};

    for (int kb = 0; kb < K; kb += KC) {
        const int kend = (kb + KC < K) ? kb + KC : K;
        for (int k0 = kb; k0 < kend; k0 += 16) {
            // ---- stage A tile: 128 rows x 16 k
#pragma unroll
            for (int it = 0; it < 2; ++it) {
                int idx = tid + it * 256;
                int row = idx >> 2, q = idx & 3;
                int gr = bm + row, gk = k0 + q * 4;
                float4 v = make_float4(0.f, 0.f, 0.f, 0.f);
                if (gr < M) {
                    if (gk + 3 < kend) {
                        v = *(const float4*)(A + (size_t)gr * K + gk);
                    } else {
                        float* vp = (float*)&v;
#pragma unroll
                        for (int e = 0; e < 4; ++e)
                            if (gk + e < kend) vp[e] = A[(size_t)gr * K + gk + e];
                    }
                }
                float* vp = (float*)&v;
#pragma unroll
                for (int e = 0; e < 4; ++e) As[q * 4 + e][row] = vp[e];
            }
            // ---- stage B tile
            if (!TRANSB) {
#pragma unroll
                for (int it = 0; it < 2; ++it) {
                    int idx = tid + it * 256;
                    int kk = idx >> 5, cq = idx & 31;
                    int gk = k0 + kk, c = cq * 4, gc = bn + c;
                    float4 v = make_float4(0.f, 0.f, 0.f, 0.f);
                    if (gk < kend) {
                        if (gc + 3 < N) {
                            v = *(const float4*)(B + (size_t)gk * N + gc);
                        } else {
                            float* vp = (float*)&v;
#pragma unroll
                            for (int e = 0; e < 4; ++e)
                                if (gc + e < N) vp[e] = B[(size_t)gk * N + gc + e];
                        }
                    }
                    *(float4*)&Bs[kk][c] = v;
                }
            } else {
#pragma unroll
                for (int it = 0; it < 2; ++it) {
                    int idx = tid + it * 256;
                    int row = idx >> 2, q = idx & 3;
                    int gc = bn + row, gk = k0 + q * 4;
                    float4 v = make_float4(0.f, 0.f, 0.f, 0.f);
                    if (gc < N) {
                        if (gk + 3 < kend) {
                            v = *(const float4*)(B + (size_t)gc * K + gk);
                        } else {
                            float* vp = (float*)&v;
#pragma unroll
                            for (int e = 0; e < 4; ++e)
                                if (gk + e < kend) vp[e] = B[(size_t)gc * K + gk + e];
                        }
                    }
                    float* vp = (float*)&v;
#pragma unroll
                    for (int e = 0; e < 4; ++e) Bs[q * 4 + e][row] = vp[e];
                }
            }
            __syncthreads();
#pragma unroll
            for (int kk = 0; kk < 16; ++kk) {
                float a[8], b[8];
                *(float4*)&a[0] = *(const float4*)&As[kk][ty * 4];
                *(float4*)&a[4] = *(const float4*)&As[kk][ty * 4 + 64];
                *(float4*)&b[0] = *(const float4*)&Bs[kk][tx * 4];
                *(float4*)&b[4] = *(const float4*)&Bs[kk][tx * 4 + 64];
#pragma unroll
                for (int i = 0; i < 8; ++i)
#pragma unroll
                    for (int j = 0; j < 8; ++j)
                        blk[i][j] = fmaf(a[i], b[j], blk[i][j]);
            }
            __syncthreads();
        }
        // fold KC block (OpenBLAS store-then-add)
#pragma unroll
        for (int i = 0; i < 8; ++i)
#pragma unroll
            for (int j = 0; j < 8; ++j) {
                acc[i][j] = __fadd_rn(acc[i][j], blk[i][j]);
                blk[i][j] = 0.f;
            }
    }

#pragma unroll
    for (int i = 0; i < 8; ++i) {
        int r = bm + ty * 4 + (i & 3) + (i >> 2) * 64;
        if (r >= M) continue;
#pragma unroll
        for (int j = 0; j < 8; ++j) {
            int c = bn + tx * 4 + (j & 3) + (j >> 2) * 64;
            if (c >= N) continue;
            float v = acc[i][j];
            if (EPI == 0) {
                C[(size_t)r * N + c] = v;
            } else if (EPI == 1) {
                float s = __fadd_rn(v, bias[c]);
                C[(size_t)r * N + c] = (s >= 0.f) ? s : __fmul_rn(LEAKY, s);
            } else {
                float den = fmaxf(__fmul_rn(wn[r], wn[c]), 1e-8f);
                C[(size_t)r * N + c] = __fsub_rn(1.0f, __fdiv_rn(v, den));
            }
        }
    }
}

// ---------------------------------------------------------------------------
// numpy pairwise_sum exact replica. XF=0: fl(v*v); XF=1: |v|.
// ---------------------------------------------------------------------------
template<int XF>
__device__ float xf(float v)
{
    if (XF == 0) return __fmul_rn(v, v);
    return fabsf(v);
}

template<int XF>
__device__ float np_pairwise(const float* a, int n)
{
    if (n < 8) {
        float r = 0.f;
        for (int i = 0; i < n; ++i) r = __fadd_rn(r, xf<XF>(a[i]));
        return r;
    }
    if (n <= 128) {
        float r[8];
#pragma unroll
        for (int j = 0; j < 8; ++j) r[j] = xf<XF>(a[j]);
        int i = 8;
        const int lim = n - (n & 7);
        for (; i < lim; i += 8)
#pragma unroll
            for (int j = 0; j < 8; ++j) r[j] = __fadd_rn(r[j], xf<XF>(a[i + j]));
        float res = __fadd_rn(__fadd_rn(__fadd_rn(r[0], r[1]), __fadd_rn(r[2], r[3])),
                              __fadd_rn(__fadd_rn(r[4], r[5]), __fadd_rn(r[6], r[7])));
        for (; i < n; ++i) res = __fadd_rn(res, xf<XF>(a[i]));
        return res;
    }
    int n2 = (n / 2) & ~7;
    return __fadd_rn(np_pairwise<XF>(a, n2), np_pairwise<XF>(a + n2, n - n2));
}

__global__ __launch_bounds__(64)
void rownorm_np_k(const float* __restrict__ X, float* __restrict__ wn, int D)
{
    int row = blockIdx.x * 64 + threadIdx.x;
    if (row >= NN) return;
    wn[row] = __fsqrt_rn(np_pairwise<0>(X + (size_t)row * D, D));
}

__global__ __launch_bounds__(64)
void rowabs_np_k(const float* __restrict__ A, float* __restrict__ rs, int n)
{
    int row = blockIdx.x * 64 + threadIdx.x;
    if (row >= NN) return;
    rs[row] = fmaxf(np_pairwise<1>(A + (size_t)row * n, n), 1e-12f);
}

// ---------------------------------------------------------------------------
// exact rank select (radix, 32-bit monotone keys)
// ---------------------------------------------------------------------------
__global__ void init_k(unsigned* __restrict__ hist, unsigned* __restrict__ state,
                       const void* __restrict__ epn)
{
    hist[threadIdx.x] = 0;
    if (threadIdx.x == 0) {
        int k = ((const int*)epn)[0];
        if (k <= 0 || k > 4000) {
            float f = ((const float*)epn)[0];
            if (f > 0.f && f <= 4000.f) k = (int)f;
            else {
                long long ll = ((const long long*)epn)[0];
                if (ll > 0 && ll <= 4000) k = (int)ll;
                else {
                    double dd = ((const double*)epn)[0];
                    k = (dd > 0.0 && dd <= 4000.0) ? (int)dd : 10;
                }
            }
        }
        state[0] = 0u;
        state[1] = (unsigned)(k * NN);
    }
}

__global__ __launch_bounds__(256)
void hist_k(const float* __restrict__ dist, unsigned* __restrict__ hist,
            const unsigned* __restrict__ state, int shift, size_t n)
{
    __shared__ unsigned lh[256];
    lh[threadIdx.x] = 0;
    __syncthreads();
    const unsigned prefix = state[0];
    const size_t stride = (size_t)gridDim.x * 256;
    for (size_t idx = (size_t)blockIdx.x * 256 + threadIdx.x; idx < n; idx += stride) {
        unsigned u = __float_as_uint(dist[idx]);
        unsigned key = (u & 0x80000000u) ? ~u : (u | 0x80000000u);
        bool ok = (shift == 24) || ((key >> (shift + 8)) == prefix);
        if (ok) atomicAdd(&lh[(key >> shift) & 0xFFu], 1u);
    }
    __syncthreads();
    if (lh[threadIdx.x]) atomicAdd(&hist[threadIdx.x], lh[threadIdx.x]);
}

__global__ __launch_bounds__(256)
void scan_k(unsigned* __restrict__ hist, unsigned* __restrict__ state,
            int shift, float* __restrict__ param)
{
    const int tid = threadIdx.x;
    unsigned h = hist[tid];
    hist[tid] = 0;
    __shared__ unsigned sh[256];
    sh[tid] = h;
    __syncthreads();
    for (int off = 1; off < 256; off <<= 1) {
        unsigned v = (tid >= off) ? sh[tid - off] : 0;
        __syncthreads();
        sh[tid] += v;
        __syncthreads();
    }
    const unsigned incl = sh[tid], excl = incl - h;
    const unsigned krem = state[1];
    if (krem >= excl && krem < incl) {
        unsigned np = (state[0] << 8) | (unsigned)tid;
        state[0] = np;
        state[1] = krem - excl;
        if (shift == 0) {
            unsigned u = (np & 0x80000000u) ? (np ^ 0x80000000u) : ~np;
            *param = __uint_as_float(u);
        }
    }
}

// ---------------------------------------------------------------------------
// dist -> unnormalized adjacency (in place), diag = 1
// ---------------------------------------------------------------------------
__global__ __launch_bounds__(256)
void thresh_k(float* __restrict__ adj, const float* __restrict__ param, int n)
{
    const int i = blockIdx.y;
    const int j = blockIdx.x * 256 + threadIdx.x;
    if (j >= n) return;
    const float p = *param;
    const size_t idx = (size_t)i * n + j;
    float d = adj[idx];
    float a = (d <= p && i != j) ? __fsub_rn(1.0f, d) : 0.0f;
    if (i == j) a = 1.0f;
    adj[idx] = a;
}

// tiled max-symmetrize: coalesced both sides via LDS transpose staging
__global__ __launch_bounds__(256)
void sym_tile_k(float* __restrict__ adj, int n)
{
    __shared__ float TB[64][65];
    __shared__ float TM[64][65];
    const int nt = (n + 63) >> 6;
    int bi = 0, rem = blockIdx.x;
    while (rem >= nt - bi) { rem -= nt - bi; ++bi; }
    const int bj = bi + rem;
    const int tid = threadIdx.x;
    const int r0i = bi * 64, r0j = bj * 64;

    // mirror tile (rows r0j.., cols r0i..) -> TB[q][c]
#pragma unroll
    for (int it = 0; it < 16; ++it) {
        int idx = tid + it * 256;
        int q = idx >> 6, c = idx & 63;
        int gr = r0j + q, gc = r0i + c;
        TB[q][c] = (gr < n && gc < n) ? adj[(size_t)gr * n + gc] : 0.f;
    }
    __syncthreads();
    // A tile (rows r0i.., cols r0j..): m = max(a, mirror^T)
#pragma unroll
    for (int it = 0; it < 16; ++it) {
        int idx = tid + it * 256;
        int q = idx >> 6, c = idx & 63;
        int gr = r0i + q, gc = r0j + c;
        float m = 0.f;
        if (gr < n && gc < n) {
            float a = (bi == bj) ? TB[q][c] : adj[(size_t)gr * n + gc];
            m = fmaxf(a, TB[c][q]);
            adj[(size_t)gr * n + gc] = m;
        }
        TM[q][c] = m;
    }
    __syncthreads();
    if (bi != bj) {
#pragma unroll
        for (int it = 0; it < 16; ++it) {
            int idx = tid + it * 256;
            int q = idx >> 6, c = idx & 63;
            int gr = r0j + q, gc = r0i + c;
            if (gr < n && gc < n) adj[(size_t)gr * n + gc] = TM[c][q];
        }
    }
}

__global__ __launch_bounds__(256)
void norm_k(float* __restrict__ adj, const float* __restrict__ rs, int n)
{
    const int i = blockIdx.y;
    const int j = blockIdx.x * 256 + threadIdx.x;
    if (j >= n) return;
    const size_t idx = (size_t)i * n + j;
    adj[idx] = __fdiv_rn(adj[idx], rs[i]);
}

// ---------------------------------------------------------------------------
// CSR build (ascending k per row) + bit-exact SpMM with lazy KC folds.
// Skipping zeros is exact: adj values are +0 or positive; fmaf(+-0,b,acc)
// and the empty-block folds are identities (verified reasoning R7).
// ---------------------------------------------------------------------------
__global__ __launch_bounds__(256)
void count_k(const float* __restrict__ A, int* __restrict__ cnt, int n)
{
    const int gw = (blockIdx.x * blockDim.x + threadIdx.x) >> 6;
    if (gw >= n) return;
    const int lane = threadIdx.x & 63;
    int c = 0;
    for (int k0 = 0; k0 < n; k0 += 64) {
        int k = k0 + lane;
        bool nz = (k < n) && (A[(size_t)gw * n + k] != 0.0f);
        unsigned long long m = __ballot(nz);
        c += (int)__popcll(m);
    }
    if (lane == 0) cnt[gw] = c;
}

__global__ __launch_bounds__(1024)
void scanrows_k(const int* __restrict__ cnt, int* __restrict__ roff)
{
    const int t = threadIdx.x;
    int vals[4];
    int s0 = 0;
#pragma unroll
    for (int e = 0; e < 4; ++e) {
        int r = t * 4 + e;
        vals[e] = (r < NN) ? cnt[r] : 0;
        s0 += vals[e];
    }
    __shared__ int sh[1024];
    sh[t] = s0;
    __syncthreads();
    for (int off = 1; off < 1024; off <<= 1) {
        int v = (t >= off) ? sh[t - off] : 0;
        __syncthreads();
        sh[t] += v;
        __syncthreads();
    }
    int excl = sh[t] - s0;
#pragma unroll
    for (int e = 0; e < 4; ++e) {
        int r = t * 4 + e;
        if (r <= NN) roff[r] = excl;
        excl += vals[e];
    }
    if (t == 1023) roff[NN] = sh[1023];
}

__global__ __launch_bounds__(256)
void fill_k(const float* __restrict__ A, const int* __restrict__ roff,
            int* __restrict__ ridx, float* __restrict__ rval, int n)
{
    const int gw = (blockIdx.x * blockDim.x + threadIdx.x) >> 6;
    if (gw >= n) return;
    const int lane = threadIdx.x & 63;
    int base = roff[gw];
    const unsigned long long ltmask = (lane == 63) ? ~0ULL >> 1
                                                   : ((1ULL << lane) - 1);
    for (int k0 = 0; k0 < n; k0 += 64) {
        int k = k0 + lane;
        float v = (k < n) ? A[(size_t)gw * n + k] : 0.f;
        bool nz = (v != 0.0f);
        unsigned long long m = __ballot(nz);
        if (nz) {
            int pos = base + (int)__popcll(m & ltmask);
            ridx[pos] = k;
            rval[pos] = v;
        }
        base += (int)__popcll(m);
    }
}

__global__ __launch_bounds__(256)
void spmm_k(const int* __restrict__ roff, const int* __restrict__ ridx,
            const float* __restrict__ rval, const float* __restrict__ T,
            const float* __restrict__ bias, float* __restrict__ H, int ncols)
{
    __shared__ int ks[128];
    __shared__ float vs[128];
    const int r = blockIdx.x;
    const int tid = threadIdx.x;
    const int c0 = tid, c1 = tid + 256;
    const bool ok0 = c0 < ncols, ok1 = c1 < ncols;
    float acc0 = 0.f, blk0 = 0.f, acc1 = 0.f, blk1 = 0.f;
    int nb = KC;
    const int s = roff[r], e = roff[r + 1];
    for (int base = s; base < e; base += 128) {
        const int m = (e - base < 128) ? (e - base) : 128;
        __syncthreads();
        if (tid < m) { ks[tid] = ridx[base + tid]; vs[tid] = rval[base + tid]; }
        __syncthreads();
        for (int t = 0; t < m; ++t) {
            const int k = ks[t];
            const float v = vs[t];
            while (k >= nb) {   // lazy KC folds at original-k boundaries
                acc0 = __fadd_rn(acc0, blk0); blk0 = 0.f;
                acc1 = __fadd_rn(acc1, blk1); blk1 = 0.f;
                nb += KC;
            }
            const float* Tr = T + (size_t)k * ncols;
            if (ok0) blk0 = fmaf(v, Tr[c0], blk0);
            if (ok1) blk1 = fmaf(v, Tr[c1], blk1);
        }
    }
    acc0 = __fadd_rn(acc0, blk0);
    acc1 = __fadd_rn(acc1, blk1);
    if (ok0) {
        float s0 = __fadd_rn(acc0, bias[c0]);
        H[(size_t)r * ncols + c0] = (s0 >= 0.f) ? s0 : __fmul_rn(LEAKY, s0);
    }
    if (ok1) {
        float s1 = __fadd_rn(acc1, bias[c1]);
        H[(size_t)r * ncols + c1] = (s1 >= 0.f) ? s1 : __fmul_rn(LEAKY, s1);
    }
}

// ---------------------------------------------------------------------------

static inline dim3 g128(int M, int N)
{
    return dim3((N + 127) / 128, (M + 127) / 128);
}

extern "C" void kernel_launch(void* const* d_in, const int* in_sizes, int n_in,
                              void* d_out, int out_size, void* d_ws, size_t ws_size,
                              hipStream_t stream)
{
    const void*  epn  = d_in[0];
    const float* x    = (const float*)d_in[1];
    const float* adj0 = (const float*)d_in[2];
    const float* w1   = (const float*)d_in[3];
    const float* b1   = (const float*)d_in[4];
    const float* w2   = (const float*)d_in[5];
    const float* b2   = (const float*)d_in[6];
    const float* w3   = (const float*)d_in[7];
    const float* b3   = (const float*)d_in[8];
    float* out = (float*)d_out;

    char* ws = (char*)d_ws;
    float*    dist  = (float*)   ws;                       // 64,000,000
    float*    Tbuf  = (float*)  (ws + 64000000);           //  6,400,000
    float*    H1    = (float*)  (ws + 70400000);           //  6,400,000
    float*    H2    = (float*)  (ws + 76800000);           //  6,400,000
    float*    wn    = (float*)  (ws + 83200000);           //     16,000
    float*    rs    = (float*)  (ws + 83216000);           //     16,000
    unsigned* hist  = (unsigned*)(ws + 83232000);          //      1,024
    unsigned* state = (unsigned*)(ws + 83233024);          //          8
    float*    param = (float*)  (ws + 83233032);           //          4 (+pad)
    int*      cnt   = (int*)    (ws + 83233040);           //     16,000
    int*      roff  = (int*)    (ws + 83249040);           //     16,008
    int*      ridx  = (int*)    (ws + 83265048);           // 16,000,000
    float*    rval  = (float*)  (ws + 99265048);           // 16,000,000
    const bool use_csr = (ws_size >= 115265048ULL + 64);

    const size_t n2 = (size_t)NN * NN;
    const int shifts[4] = {24, 16, 8, 0};
    const dim3 rowgrid((NN + 255) / 256, NN);
    const int ntile = (NN + 63) / 64;
    const int nsym = ntile * (ntile + 1) / 2;

    // sparse (or dense-fallback) aggregation: H = leaky(Aadj @ T + bias)
    auto aggregate = [&](const float* Aadj, const float* Tm, const float* bias,
                         float* Hout, int ncols) {
        if (use_csr) {
            count_k<<<(NN + 3) / 4, 256, 0, stream>>>(Aadj, cnt, NN);
            scanrows_k<<<1, 1024, 0, stream>>>(cnt, roff);
            fill_k<<<(NN + 3) / 4, 256, 0, stream>>>(Aadj, roff, ridx, rval, NN);
            spmm_k<<<NN, 256, 0, stream>>>(roff, ridx, rval, Tm, bias, Hout, ncols);
        } else {
            gemm128_k<1, false><<<g128(NN, ncols), 256, 0, stream>>>(
                Aadj, Tm, Hout, NN, ncols, NN, bias, nullptr);
        }
    };

    auto genadj = [&](const float* H) {
        rownorm_np_k<<<(NN + 63) / 64, 64, 0, stream>>>(H, wn, 400);
        gemm128_k<2, true><<<g128(NN, NN), 256, 0, stream>>>(
            H, H, dist, NN, NN, 400, nullptr, wn);
        init_k<<<1, 256, 0, stream>>>(hist, state, epn);
        for (int p = 0; p < 4; ++p) {
            hist_k<<<2048, 256, 0, stream>>>(dist, hist, state, shifts[p], n2);
            scan_k<<<1, 256, 0, stream>>>(hist, state, shifts[p], param);
        }
        thresh_k<<<rowgrid, 256, 0, stream>>>(dist, param, NN);
        sym_tile_k<<<nsym, 256, 0, stream>>>(dist, NN);
        rowabs_np_k<<<(NN + 63) / 64, 64, 0, stream>>>(dist, rs, NN);
        norm_k<<<rowgrid, 256, 0, stream>>>(dist, rs, NN);
    };

    // ---- Layer 1
    gemm128_k<0, false><<<g128(NN, 400), 256, 0, stream>>>(
        x, w1, Tbuf, NN, 400, 1000, nullptr, nullptr);
    aggregate(adj0, Tbuf, b1, H1, 400);

    // ---- gen_adj(H1) + Layer 2
    genadj(H1);
    gemm128_k<0, false><<<g128(NN, 400), 256, 0, stream>>>(
        H1, w2, Tbuf, NN, 400, 400, nullptr, nullptr);
    aggregate(dist, Tbuf, b2, H2, 400);

    // ---- gen_adj(H2) + Layer 3
    genadj(H2);
    gemm128_k<0, false><<<g128(NN, 200), 256, 0, stream>>>(
        H2, w3, Tbuf, NN, 200, 400, nullptr, nullptr);
    aggregate(dist, Tbuf, b3, out, 200);
}

// Round 8
// 1537.480 us; speedup vs baseline: 2.5055x; 1.2787x over previous
//
#include <hip/hip_runtime.h>
#include <math.h>

#define NN 4000
#define KC 384      // OpenBLAS SGEMM_DEFAULT_Q — fold granularity (bit-frozen)
#define LEAKY 0.25f

// ===========================================================================
// Bit-frozen arithmetic (verified R6/R7, absmax must remain 0.001953125):
//   - per-output dot: blk = fmaf(a_k,b_k,blk) strict ascending k within each
//     KC=384 block; across blocks acc = __fadd_rn(acc, blk) in order.
//   - reductions: numpy pairwise_sum tree; elementwise: *_rn intrinsics.
// This round: KC blocks -> separate kernel passes (64 acc regs, occupancy),
// LDS-staged tree-parallel reductions, thresh+sym fusion, norm folded to CSR.
// ===========================================================================

template<int EPI>
__device__ inline float epi_apply(float v, int r, int c,
                                  const float* __restrict__ bias,
                                  const float* __restrict__ wn)
{
    if (EPI == 1) {
        float s = __fadd_rn(v, bias[c]);
        return (s >= 0.f) ? s : __fmul_rn(LEAKY, s);
    }
    if (EPI == 2) {
        float den = fmaxf(__fmul_rn(wn[r], wn[c]), 1e-8f);
        return __fsub_rn(1.0f, __fdiv_rn(v, den));
    }
    return v;
}

template<int EPI, bool TRANSB, bool FIRST, bool LAST>
__global__ __launch_bounds__(256, 4)
void gemm_pass_k(const float* __restrict__ A, const float* __restrict__ B,
                 float* __restrict__ C, int M, int N, int K, int kb, int kend,
                 const float* __restrict__ bias, const float* __restrict__ wn)
{
    __shared__ float As[16][132];
    __shared__ float Bs[16][132];
    const int tid = threadIdx.x;
    const int tx = tid & 15, ty = tid >> 4;
    const int bm = blockIdx.y * 128, bn = blockIdx.x * 128;

    float blk[8][8] = {};

    for (int k0 = kb; k0 < kend; k0 += 16) {
#pragma unroll
        for (int it = 0; it < 2; ++it) {
            int idx = tid + it * 256;
            int row = idx >> 2, q = idx & 3;
            int gr = bm + row, gk = k0 + q * 4;
            float4 v = make_float4(0.f, 0.f, 0.f, 0.f);
            if (gr < M) {
                if (gk + 3 < kend) {
                    v = *(const float4*)(A + (size_t)gr * K + gk);
                } else {
                    float* vp = (float*)&v;
#pragma unroll
                    for (int e = 0; e < 4; ++e)
                        if (gk + e < kend) vp[e] = A[(size_t)gr * K + gk + e];
                }
            }
            float* vp = (float*)&v;
#pragma unroll
            for (int e = 0; e < 4; ++e) As[q * 4 + e][row] = vp[e];
        }
        if (!TRANSB) {
#pragma unroll
            for (int it = 0; it < 2; ++it) {
                int idx = tid + it * 256;
                int kk = idx >> 5, cq = idx & 31;
                int gk = k0 + kk, c = cq * 4, gc = bn + c;
                float4 v = make_float4(0.f, 0.f, 0.f, 0.f);
                if (gk < kend) {
                    if (gc + 3 < N) {
                        v = *(const float4*)(B + (size_t)gk * N + gc);
                    } else {
                        float* vp = (float*)&v;
#pragma unroll
                        for (int e = 0; e < 4; ++e)
                            if (gc + e < N) vp[e] = B[(size_t)gk * N + gc + e];
                    }
                }
                *(float4*)&Bs[kk][c] = v;
            }
        } else {
#pragma unroll
            for (int it = 0; it < 2; ++it) {
                int idx = tid + it * 256;
                int row = idx >> 2, q = idx & 3;
                int gc = bn + row, gk = k0 + q * 4;
                float4 v = make_float4(0.f, 0.f, 0.f, 0.f);
                if (gc < N) {
                    if (gk + 3 < kend) {
                        v = *(const float4*)(B + (size_t)gc * K + gk);
                    } else {
                        float* vp = (float*)&v;
#pragma unroll
                        for (int e = 0; e < 4; ++e)
                            if (gk + e < kend) vp[e] = B[(size_t)gc * K + gk + e];
                    }
                }
                float* vp = (float*)&v;
#pragma unroll
                for (int e = 0; e < 4; ++e) Bs[q * 4 + e][row] = vp[e];
            }
        }
        __syncthreads();
#pragma unroll
        for (int kk = 0; kk < 16; ++kk) {
            float a[8], b[8];
            *(float4*)&a[0] = *(const float4*)&As[kk][ty * 4];
            *(float4*)&a[4] = *(const float4*)&As[kk][ty * 4 + 64];
            *(float4*)&b[0] = *(const float4*)&Bs[kk][tx * 4];
            *(float4*)&b[4] = *(const float4*)&Bs[kk][tx * 4 + 64];
#pragma unroll
            for (int i = 0; i < 8; ++i)
#pragma unroll
                for (int j = 0; j < 8; ++j)
                    blk[i][j] = fmaf(a[i], b[j], blk[i][j]);   // strict asc. k
        }
        __syncthreads();
    }

#pragma unroll
    for (int i = 0; i < 8; ++i) {
        int r = bm + ty * 4 + (i & 3) + (i >> 2) * 64;
        if (r >= M) continue;
        float* Crow = C + (size_t)r * N;
#pragma unroll
        for (int h = 0; h < 2; ++h) {
            int c = bn + tx * 4 + h * 64;
            float v[4];
#pragma unroll
            for (int e = 0; e < 4; ++e) v[e] = blk[i][h * 4 + e];
            if (c + 3 < N) {
                if (!FIRST) {
                    float4 o = *(const float4*)(Crow + c);
                    v[0] = __fadd_rn(o.x, v[0]); v[1] = __fadd_rn(o.y, v[1]);
                    v[2] = __fadd_rn(o.z, v[2]); v[3] = __fadd_rn(o.w, v[3]);
                }
                if (LAST) {
#pragma unroll
                    for (int e = 0; e < 4; ++e)
                        v[e] = epi_apply<EPI>(v[e], r, c + e, bias, wn);
                }
                float4 s; s.x = v[0]; s.y = v[1]; s.z = v[2]; s.w = v[3];
                *(float4*)(Crow + c) = s;
            } else {
#pragma unroll
                for (int e = 0; e < 4; ++e) {
                    if (c + e >= N) continue;
                    float vv = v[e];
                    if (!FIRST) vv = __fadd_rn(Crow[c + e], vv);
                    if (LAST) vv = epi_apply<EPI>(vv, r, c + e, bias, wn);
                    Crow[c + e] = vv;
                }
            }
        }
    }
}

// ---------------------------------------------------------------------------
template<int XF>
__device__ float xf(float v)
{
    if (XF == 0) return __fmul_rn(v, v);
    return fabsf(v);
}

template<int XF>
__device__ float np_pairwise(const float* a, int n)
{
    if (n < 8) {
        float r = 0.f;
        for (int i = 0; i < n; ++i) r = __fadd_rn(r, xf<XF>(a[i]));
        return r;
    }
    if (n <= 128) {
        float r[8];
#pragma unroll
        for (int j = 0; j < 8; ++j) r[j] = xf<XF>(a[j]);
        int i = 8;
        const int lim = n - (n & 7);
        for (; i < lim; i += 8)
#pragma unroll
            for (int j = 0; j < 8; ++j) r[j] = __fadd_rn(r[j], xf<XF>(a[i + j]));
        float res = __fadd_rn(__fadd_rn(__fadd_rn(r[0], r[1]), __fadd_rn(r[2], r[3])),
                              __fadd_rn(__fadd_rn(r[4], r[5]), __fadd_rn(r[6], r[7])));
        for (; i < n; ++i) res = __fadd_rn(res, xf<XF>(a[i]));
        return res;
    }
    int n2 = (n / 2) & ~7;
    return __fadd_rn(np_pairwise<XF>(a, n2), np_pairwise<XF>(a + n2, n - n2));
}

// block-per-row, LDS-staged; leaves on lanes match np's recursion tree exactly
__global__ __launch_bounds__(256)
void rownorm2_k(const float* __restrict__ X, float* __restrict__ wn)
{
    __shared__ float buf[400];
    __shared__ float leaf[4];
    const int row = blockIdx.x;
    const float* Xr = X + (size_t)row * 400;
    for (int i = threadIdx.x; i < 100; i += 256)
        *(float4*)&buf[i * 4] = *(const float4*)(Xr + i * 4);
    __syncthreads();
    if (threadIdx.x < 4) {
        const int off = (threadIdx.x >> 1) * 200 + ((threadIdx.x & 1) ? 96 : 0);
        const int len = (threadIdx.x & 1) ? 104 : 96;
        leaf[threadIdx.x] = np_pairwise<0>(buf + off, len);
    }
    __syncthreads();
    if (threadIdx.x == 0) {
        float s = __fadd_rn(__fadd_rn(leaf[0], leaf[1]),
                            __fadd_rn(leaf[2], leaf[3]));
        wn[row] = __fsqrt_rn(s);
    }
}

__global__ __launch_bounds__(256)
void rowabs2_k(const float* __restrict__ A, float* __restrict__ rs)
{
    __shared__ float buf[4000];
    __shared__ float leaf[8];
    const int row = blockIdx.x;
    const float* Ar = A + (size_t)row * 4000;
    for (int i = threadIdx.x; i < 1000; i += 256)
        *(float4*)&buf[i * 4] = *(const float4*)(Ar + i * 4);
    __syncthreads();
    if (threadIdx.x < 8) {
        const int off = (threadIdx.x >> 1) * 1000 + ((threadIdx.x & 1) ? 496 : 0);
        const int len = (threadIdx.x & 1) ? 504 : 496;
        leaf[threadIdx.x] = np_pairwise<1>(buf + off, len);
    }
    __syncthreads();
    if (threadIdx.x == 0) {
        float s = __fadd_rn(
            __fadd_rn(__fadd_rn(leaf[0], leaf[1]), __fadd_rn(leaf[2], leaf[3])),
            __fadd_rn(__fadd_rn(leaf[4], leaf[5]), __fadd_rn(leaf[6], leaf[7])));
        rs[row] = fmaxf(s, 1e-12f);
    }
}

// ---------------------------------------------------------------------------
__global__ void init_k(unsigned* __restrict__ hist, unsigned* __restrict__ state,
                       const void* __restrict__ epn)
{
    hist[threadIdx.x] = 0;
    if (threadIdx.x == 0) {
        int k = ((const int*)epn)[0];
        if (k <= 0 || k > 4000) {
            float f = ((const float*)epn)[0];
            if (f > 0.f && f <= 4000.f) k = (int)f;
            else {
                long long ll = ((const long long*)epn)[0];
                if (ll > 0 && ll <= 4000) k = (int)ll;
                else {
                    double dd = ((const double*)epn)[0];
                    k = (dd > 0.0 && dd <= 4000.0) ? (int)dd : 10;
                }
            }
        }
        state[0] = 0u;
        state[1] = (unsigned)(k * NN);
    }
}

__global__ __launch_bounds__(256)
void hist_k(const float* __restrict__ dist, unsigned* __restrict__ hist,
            const unsigned* __restrict__ state, int shift, size_t n)
{
    __shared__ unsigned lh[256];
    lh[threadIdx.x] = 0;
    __syncthreads();
    const unsigned prefix = state[0];
    const size_t stride = (size_t)gridDim.x * 256;
    for (size_t idx = (size_t)blockIdx.x * 256 + threadIdx.x; idx < n; idx += stride) {
        unsigned u = __float_as_uint(dist[idx]);
        unsigned key = (u & 0x80000000u) ? ~u : (u | 0x80000000u);
        bool ok = (shift == 24) || ((key >> (shift + 8)) == prefix);
        if (ok) atomicAdd(&lh[(key >> shift) & 0xFFu], 1u);
    }
    __syncthreads();
    if (lh[threadIdx.x]) atomicAdd(&hist[threadIdx.x], lh[threadIdx.x]);
}

__global__ __launch_bounds__(256)
void scan_k(unsigned* __restrict__ hist, unsigned* __restrict__ state,
            int shift, float* __restrict__ param)
{
    const int tid = threadIdx.x;
    unsigned h = hist[tid];
    hist[tid] = 0;
    __shared__ unsigned sh[256];
    sh[tid] = h;
    __syncthreads();
    for (int off = 1; off < 256; off <<= 1) {
        unsigned v = (tid >= off) ? sh[tid - off] : 0;
        __syncthreads();
        sh[tid] += v;
        __syncthreads();
    }
    const unsigned incl = sh[tid], excl = incl - h;
    const unsigned krem = state[1];
    if (krem >= excl && krem < incl) {
        unsigned np = (state[0] << 8) | (unsigned)tid;
        state[0] = np;
        state[1] = krem - excl;
        if (shift == 0) {
            unsigned u = (np & 0x80000000u) ? (np ^ 0x80000000u) : ~np;
            *param = __uint_as_float(u);
        }
    }
}

// ---------------------------------------------------------------------------
__device__ inline float thr_f(float d, int i, int j, float p)
{
    float a = (d <= p && i != j) ? __fsub_rn(1.0f, d) : 0.0f;
    return (i == j) ? 1.0f : a;
}

__global__ __launch_bounds__(256)
void symthresh_k(float* __restrict__ adj, const float* __restrict__ param, int n)
{
    __shared__ float TB[64][65];
    __shared__ float TM[64][65];
    const float p = *param;
    const int nt = (n + 63) >> 6;
    int bi = 0, rem = blockIdx.x;
    while (rem >= nt - bi) { rem -= nt - bi; ++bi; }
    const int bj = bi + rem;
    const int tid = threadIdx.x;
    const int r0i = bi * 64, r0j = bj * 64;

#pragma unroll
    for (int it = 0; it < 16; ++it) {
        int idx = tid + it * 256;
        int q = idx >> 6, c = idx & 63;
        int gr = r0j + q, gc = r0i + c;
        TB[q][c] = (gr < n && gc < n)
                   ? thr_f(adj[(size_t)gr * n + gc], gr, gc, p) : 0.f;
    }
    __syncthreads();
#pragma unroll
    for (int it = 0; it < 16; ++it) {
        int idx = tid + it * 256;
        int q = idx >> 6, c = idx & 63;
        int gr = r0i + q, gc = r0j + c;
        float m = 0.f;
        if (gr < n && gc < n) {
            float a = (bi == bj) ? TB[q][c]
                                 : thr_f(adj[(size_t)gr * n + gc], gr, gc, p);
            m = fmaxf(a, TB[c][q]);
            adj[(size_t)gr * n + gc] = m;
        }
        TM[q][c] = m;
    }
    __syncthreads();
    if (bi != bj) {
#pragma unroll
        for (int it = 0; it < 16; ++it) {
            int idx = tid + it * 256;
            int q = idx >> 6, c = idx & 63;
            int gr = r0j + q, gc = r0i + c;
            if (gr < n && gc < n) adj[(size_t)gr * n + gc] = TM[c][q];
        }
    }
}

__global__ __launch_bounds__(256)
void norm_k(float* __restrict__ adj, const float* __restrict__ rs, int n)
{
    const int i = blockIdx.y;
    const int j = blockIdx.x * 256 + threadIdx.x;
    if (j >= n) return;
    const size_t idx = (size_t)i * n + j;
    adj[idx] = __fdiv_rn(adj[idx], rs[i]);
}

// ---------------------------------------------------------------------------
__global__ __launch_bounds__(256)
void count_k(const float* __restrict__ A, int* __restrict__ cnt, int n)
{
    const int gw = (blockIdx.x * blockDim.x + threadIdx.x) >> 6;
    if (gw >= n) return;
    const int lane = threadIdx.x & 63;
    int c = 0;
    for (int k0 = 0; k0 < n; k0 += 64) {
        int k = k0 + lane;
        bool nz = (k < n) && (A[(size_t)gw * n + k] != 0.0f);
        unsigned long long m = __ballot(nz);
        c += (int)__popcll(m);
    }
    if (lane == 0) cnt[gw] = c;
}

__global__ __launch_bounds__(1024)
void scanrows_k(const int* __restrict__ cnt, int* __restrict__ roff)
{
    const int t = threadIdx.x;
    int vals[4];
    int s0 = 0;
#pragma unroll
    for (int e = 0; e < 4; ++e) {
        int r = t * 4 + e;
        vals[e] = (r < NN) ? cnt[r] : 0;
        s0 += vals[e];
    }
    __shared__ int sh[1024];
    sh[t] = s0;
    __syncthreads();
    for (int off = 1; off < 1024; off <<= 1) {
        int v = (t >= off) ? sh[t - off] : 0;
        __syncthreads();
        sh[t] += v;
        __syncthreads();
    }
    int excl = sh[t] - s0;
#pragma unroll
    for (int e = 0; e < 4; ++e) {
        int r = t * 4 + e;
        if (r <= NN) roff[r] = excl;
        excl += vals[e];
    }
    if (t == 1023) roff[NN] = sh[1023];
}

// DIV: divide values by rs[row] (bit-exact L1 normalization fold)
template<bool DIV>
__global__ __launch_bounds__(256)
void fill_k(const float* __restrict__ A, const int* __restrict__ roff,
            const float* __restrict__ rs, int* __restrict__ ridx,
            float* __restrict__ rval, int n)
{
    const int gw = (blockIdx.x * blockDim.x + threadIdx.x) >> 6;
    if (gw >= n) return;
    const int lane = threadIdx.x & 63;
    const float r = DIV ? rs[gw] : 1.0f;
    int base = roff[gw];
    const unsigned long long ltmask = (lane == 63) ? ~0ULL >> 1
                                                   : ((1ULL << lane) - 1);
    for (int k0 = 0; k0 < n; k0 += 64) {
        int k = k0 + lane;
        float v = (k < n) ? A[(size_t)gw * n + k] : 0.f;
        bool nz = (v != 0.0f);
        unsigned long long m = __ballot(nz);
        if (nz) {
            int pos = base + (int)__popcll(m & ltmask);
            ridx[pos] = k;
            rval[pos] = DIV ? __fdiv_rn(v, r) : v;
        }
        base += (int)__popcll(m);
    }
}

__global__ __launch_bounds__(256)
void spmm_k(const int* __restrict__ roff, const int* __restrict__ ridx,
            const float* __restrict__ rval, const float* __restrict__ T,
            const float* __restrict__ bias, float* __restrict__ H, int ncols)
{
    __shared__ int ks[128];
    __shared__ float vs[128];
    const int r = blockIdx.x;
    const int tid = threadIdx.x;
    const int c0 = tid, c1 = tid + 256;
    const bool ok0 = c0 < ncols, ok1 = c1 < ncols;
    float acc0 = 0.f, blk0 = 0.f, acc1 = 0.f, blk1 = 0.f;
    int nb = KC;
    const int s = roff[r], e = roff[r + 1];
    for (int base = s; base < e; base += 128) {
        const int m = (e - base < 128) ? (e - base) : 128;
        __syncthreads();
        if (tid < m) { ks[tid] = ridx[base + tid]; vs[tid] = rval[base + tid]; }
        __syncthreads();
        for (int t = 0; t < m; ++t) {
            const int k = ks[t];
            const float v = vs[t];
            while (k >= nb) {
                acc0 = __fadd_rn(acc0, blk0); blk0 = 0.f;
                acc1 = __fadd_rn(acc1, blk1); blk1 = 0.f;
                nb += KC;
            }
            const float* Tr = T + (size_t)k * ncols;
            if (ok0) blk0 = fmaf(v, Tr[c0], blk0);
            if (ok1) blk1 = fmaf(v, Tr[c1], blk1);
        }
    }
    acc0 = __fadd_rn(acc0, blk0);
    acc1 = __fadd_rn(acc1, blk1);
    if (ok0) {
        float s0 = __fadd_rn(acc0, bias[c0]);
        H[(size_t)r * ncols + c0] = (s0 >= 0.f) ? s0 : __fmul_rn(LEAKY, s0);
    }
    if (ok1) {
        float s1 = __fadd_rn(acc1, bias[c1]);
        H[(size_t)r * ncols + c1] = (s1 >= 0.f) ? s1 : __fmul_rn(LEAKY, s1);
    }
}

// ---------------------------------------------------------------------------
static inline dim3 g128(int M, int N)
{
    return dim3((N + 127) / 128, (M + 127) / 128);
}

template<int EPI, bool TRANSB>
static void run_gemm(const float* A, const float* B, float* C,
                     int M, int N, int K, const float* bias, const float* wn,
                     hipStream_t stream)
{
    const int nb = (K + KC - 1) / KC;
    const dim3 grid = g128(M, N);
    for (int p = 0; p < nb; ++p) {
        const int kb = p * KC;
        const int kend = (kb + KC < K) ? kb + KC : K;
        const bool first = (p == 0), last = (p == nb - 1);
        if (first && last)
            gemm_pass_k<EPI, TRANSB, true, true><<<grid, 256, 0, stream>>>(
                A, B, C, M, N, K, kb, kend, bias, wn);
        else if (first)
            gemm_pass_k<EPI, TRANSB, true, false><<<grid, 256, 0, stream>>>(
                A, B, C, M, N, K, kb, kend, bias, wn);
        else if (last)
            gemm_pass_k<EPI, TRANSB, false, true><<<grid, 256, 0, stream>>>(
                A, B, C, M, N, K, kb, kend, bias, wn);
        else
            gemm_pass_k<EPI, TRANSB, false, false><<<grid, 256, 0, stream>>>(
                A, B, C, M, N, K, kb, kend, bias, wn);
    }
}

extern "C" void kernel_launch(void* const* d_in, const int* in_sizes, int n_in,
                              void* d_out, int out_size, void* d_ws, size_t ws_size,
                              hipStream_t stream)
{
    const void*  epn  = d_in[0];
    const float* x    = (const float*)d_in[1];
    const float* adj0 = (const float*)d_in[2];
    const float* w1   = (const float*)d_in[3];
    const float* b1   = (const float*)d_in[4];
    const float* w2   = (const float*)d_in[5];
    const float* b2   = (const float*)d_in[6];
    const float* w3   = (const float*)d_in[7];
    const float* b3   = (const float*)d_in[8];
    float* out = (float*)d_out;

    char* ws = (char*)d_ws;
    float*    dist  = (float*)   ws;
    float*    Tbuf  = (float*)  (ws + 64000000);
    float*    H1    = (float*)  (ws + 70400000);
    float*    H2    = (float*)  (ws + 76800000);
    float*    wn    = (float*)  (ws + 83200000);
    float*    rs    = (float*)  (ws + 83216000);
    unsigned* hist  = (unsigned*)(ws + 83232000);
    unsigned* state = (unsigned*)(ws + 83233024);
    float*    param = (float*)  (ws + 83233032);
    int*      cnt   = (int*)    (ws + 83233040);
    int*      roff  = (int*)    (ws + 83249040);
    int*      ridx  = (int*)    (ws + 83265048);
    float*    rval  = (float*)  (ws + 99265048);
    const bool use_csr = (ws_size >= 115265048ULL + 64);

    const size_t n2 = (size_t)NN * NN;
    const int shifts[4] = {24, 16, 8, 0};
    const int ntile = (NN + 63) / 64;
    const int nsym = ntile * (ntile + 1) / 2;

    auto genadj = [&](const float* H) {
        rownorm2_k<<<NN, 256, 0, stream>>>(H, wn);
        run_gemm<2, true>(H, H, dist, NN, NN, 400, nullptr, wn, stream);
        init_k<<<1, 256, 0, stream>>>(hist, state, epn);
        for (int p = 0; p < 4; ++p) {
            hist_k<<<2048, 256, 0, stream>>>(dist, hist, state, shifts[p], n2);
            scan_k<<<1, 256, 0, stream>>>(hist, state, shifts[p], param);
        }
        symthresh_k<<<nsym, 256, 0, stream>>>(dist, param, NN);
        rowabs2_k<<<NN, 256, 0, stream>>>(dist, rs);
    };

    // agg with pre-normalized input (adj0): CSR without division
    auto aggregate_pre = [&](const float* Aadj, const float* Tm,
                             const float* bias, float* Hout, int ncols) {
        if (use_csr) {
            count_k<<<(NN + 3) / 4, 256, 0, stream>>>(Aadj, cnt, NN);
            scanrows_k<<<1, 1024, 0, stream>>>(cnt, roff);
            fill_k<false><<<(NN + 3) / 4, 256, 0, stream>>>(Aadj, roff, nullptr,
                                                            ridx, rval, NN);
            spmm_k<<<NN, 256, 0, stream>>>(roff, ridx, rval, Tm, bias, Hout, ncols);
        } else {
            run_gemm<1, false>(Aadj, Tm, Hout, NN, ncols, NN, bias, nullptr, stream);
        }
    };

    // agg with unnormalized adj (dist) + rs: CSR folds the division
    auto aggregate_rs = [&](float* Aadj, const float* Tm,
                            const float* bias, float* Hout, int ncols) {
        if (use_csr) {
            count_k<<<(NN + 3) / 4, 256, 0, stream>>>(Aadj, cnt, NN);
            scanrows_k<<<1, 1024, 0, stream>>>(cnt, roff);
            fill_k<true><<<(NN + 3) / 4, 256, 0, stream>>>(Aadj, roff, rs,
                                                           ridx, rval, NN);
            spmm_k<<<NN, 256, 0, stream>>>(roff, ridx, rval, Tm, bias, Hout, ncols);
        } else {
            norm_k<<<dim3((NN + 255) / 256, NN), 256, 0, stream>>>(Aadj, rs, NN);
            run_gemm<1, false>(Aadj, Tm, Hout, NN, ncols, NN, bias, nullptr, stream);
        }
    };

    // ---- Layer 1
    run_gemm<0, false>(x, w1, Tbuf, NN, 400, 1000, nullptr, nullptr, stream);
    aggregate_pre(adj0, Tbuf, b1, H1, 400);

    // ---- gen_adj(H1) + Layer 2
    genadj(H1);
    run_gemm<0, false>(H1, w2, Tbuf, NN, 400, 400, nullptr, nullptr, stream);
    aggregate_rs(dist, Tbuf, b2, H2, 400);

    // ---- gen_adj(H2) + Layer 3
    genadj(H2);
    run_gemm<0, false>(H2, w3, Tbuf, NN, 200, 400, nullptr, nullptr, stream);
    aggregate_rs(dist, Tbuf, b3, out, 200);
}